// Round 1
// baseline (278.486 us; speedup 1.0000x reference)
//
#include <hip/hip_runtime.h>

#define BDIM 4
#define HDIM 16
#define SDIM 4096
#define DDIM 64
#define NBH (BDIM * HDIM)

#define P1_TS 16
#define P1_NCHUNK 16
#define P1_CHUNK (SDIM / P1_NCHUNK)   // 256 rows per block

#define P2_MT 64                       // q rows per block

__device__ __forceinline__ float phi_f(float x) {
    // elu(x)+1 = x+1 (x>0) else exp(x)
    return x > 0.0f ? x + 1.0f : __expf(x);
}

// -------- Phase 1: kv[bh][d][e] = sum_s phiK[s][d]*V[s][e]; kone[bh][d] = sum_s phiK[s][d]
__global__ __launch_bounds__(256) void la_phase1(
    const float* __restrict__ K, const float* __restrict__ V,
    const float* __restrict__ mask,
    float* __restrict__ kv, float* __restrict__ kone)
{
    __shared__ float kT[P1_TS][DDIM];
    __shared__ float vT[P1_TS][DDIM];

    const int bh = blockIdx.y;
    const int b  = bh / HDIM;
    const int t  = threadIdx.x;
    const int row = t >> 4;            // 0..15 (tile row this thread loads)
    const int c4  = (t & 15) << 2;     // 0..60 (col group this thread loads)
    const int d0  = (t >> 4) << 2;     // acc tile: d rows 0..60
    const int e0  = (t & 15) << 2;     // acc tile: e cols 0..60
    const int s_base = blockIdx.x * P1_CHUNK;

    const float* Kb = K + (size_t)bh * SDIM * DDIM;
    const float* Vb = V + (size_t)bh * SDIM * DDIM;
    const float* mb = mask + (size_t)b * SDIM;

    const float scale = 0.35355339059327373f;   // 64^-0.25

    float acc[4][4] = {};
    float k1[4] = {0.f, 0.f, 0.f, 0.f};

    // prefetch first tile
    int s0 = s_base + row;
    float4 kf = *(const float4*)(Kb + (size_t)s0 * DDIM + c4);
    float4 vf = *(const float4*)(Vb + (size_t)s0 * DDIM + c4);
    float  m  = mb[s0];

    for (int st = 0; st < P1_CHUNK; st += P1_TS) {
        const float p0 = phi_f(kf.x * scale) * m;
        const float p1 = phi_f(kf.y * scale) * m;
        const float p2 = phi_f(kf.z * scale) * m;
        const float p3 = phi_f(kf.w * scale) * m;
        __syncthreads();                 // previous tile fully consumed
        kT[row][c4 + 0] = p0;
        kT[row][c4 + 1] = p1;
        kT[row][c4 + 2] = p2;
        kT[row][c4 + 3] = p3;
        *(float4*)&vT[row][c4] = vf;
        __syncthreads();

        k1[0] += p0; k1[1] += p1; k1[2] += p2; k1[3] += p3;

        // prefetch next tile (overlaps with accumulate below)
        if (st + P1_TS < P1_CHUNK) {
            const int sn = s_base + st + P1_TS + row;
            kf = *(const float4*)(Kb + (size_t)sn * DDIM + c4);
            vf = *(const float4*)(Vb + (size_t)sn * DDIM + c4);
            m  = mb[sn];
        }

        #pragma unroll
        for (int ss = 0; ss < P1_TS; ++ss) {
            const float4 a  = *(const float4*)&kT[ss][d0];  // 4-addr broadcast within wave
            const float4 v4 = *(const float4*)&vT[ss][e0];  // 2-way bank alias (free)
            acc[0][0] += a.x * v4.x; acc[0][1] += a.x * v4.y; acc[0][2] += a.x * v4.z; acc[0][3] += a.x * v4.w;
            acc[1][0] += a.y * v4.x; acc[1][1] += a.y * v4.y; acc[1][2] += a.y * v4.z; acc[1][3] += a.y * v4.w;
            acc[2][0] += a.z * v4.x; acc[2][1] += a.z * v4.y; acc[2][2] += a.z * v4.z; acc[2][3] += a.z * v4.w;
            acc[3][0] += a.w * v4.x; acc[3][1] += a.w * v4.y; acc[3][2] += a.w * v4.z; acc[3][3] += a.w * v4.w;
        }
    }

    float* kvb = kv + (size_t)bh * DDIM * DDIM;
    #pragma unroll
    for (int i = 0; i < 4; ++i)
        #pragma unroll
        for (int j = 0; j < 4; ++j)
            atomicAdd(&kvb[(d0 + i) * DDIM + e0 + j], acc[i][j]);

    // reduce k1 over the 16 row-groups sharing each column group
    __syncthreads();
    kT[row][c4 + 0] = k1[0];
    kT[row][c4 + 1] = k1[1];
    kT[row][c4 + 2] = k1[2];
    kT[row][c4 + 3] = k1[3];
    __syncthreads();
    if (t < DDIM) {
        float s1 = 0.f;
        #pragma unroll
        for (int r = 0; r < P1_TS; ++r) s1 += kT[r][t];
        atomicAdd(&kone[bh * DDIM + t], s1);
    }
}

// -------- Phase 2: out[s][e] = (sum_d phiQ[s][d]*kv[d][e]) / (sum_d phiQ[s][d]*kone[d] + 1e-8)
__global__ __launch_bounds__(256) void la_phase2(
    const float* __restrict__ Q, const float* __restrict__ mask,
    const float* __restrict__ kv, const float* __restrict__ kone,
    float* __restrict__ out)
{
    __shared__ float kvL[DDIM][DDIM];          // [d][e]
    __shared__ float pqT[DDIM][P2_MT + 4];     // [d][row], +4 keeps rows 16B-aligned
    __shared__ float koL[DDIM];

    const int bh = blockIdx.y;
    const int b  = bh / HDIM;
    const int t  = threadIdx.x;
    const int s_base = blockIdx.x * P2_MT;

    const float scale = 0.35355339059327373f;

    // load kv (4096 floats) and kone into LDS
    {
        const float4* src = (const float4*)(kv + (size_t)bh * DDIM * DDIM);
        float4* dst = (float4*)&kvL[0][0];
        #pragma unroll
        for (int i = 0; i < 4; ++i) dst[t + 256 * i] = src[t + 256 * i];
        if (t < DDIM) koL[t] = kone[bh * DDIM + t];
    }
    // load q tile, apply phi+mask, store transposed (conflict-free writes)
    {
        const float* Qb = Q + (size_t)bh * SDIM * DDIM;
        const float* mb = mask + (size_t)b * SDIM;
        const int lr = t & 15;          // row within 16-row group
        const int c4 = (t >> 4) << 2;   // col group 0..60
        #pragma unroll
        for (int k = 0; k < 4; ++k) {
            const int r = lr + 16 * k;  // 0..63
            const int s = s_base + r;
            const float4 qf = *(const float4*)(Qb + (size_t)s * DDIM + c4);
            const float mm = mb[s];
            pqT[c4 + 0][r] = phi_f(qf.x * scale) * mm;
            pqT[c4 + 1][r] = phi_f(qf.y * scale) * mm;
            pqT[c4 + 2][r] = phi_f(qf.z * scale) * mm;
            pqT[c4 + 3][r] = phi_f(qf.w * scale) * mm;
        }
    }
    __syncthreads();

    const int r0 = (t >> 4) << 2;
    const int e0 = (t & 15) << 2;
    float acc[4][4] = {};
    float nrm[4] = {0.f, 0.f, 0.f, 0.f};

    #pragma unroll 16
    for (int d = 0; d < DDIM; ++d) {
        const float4 a  = *(const float4*)&pqT[d][r0];   // broadcast within wave
        const float4 bb = *(const float4*)&kvL[d][e0];   // 2-way alias (free)
        const float ko = koL[d];                          // same-addr broadcast
        acc[0][0] += a.x * bb.x; acc[0][1] += a.x * bb.y; acc[0][2] += a.x * bb.z; acc[0][3] += a.x * bb.w;
        acc[1][0] += a.y * bb.x; acc[1][1] += a.y * bb.y; acc[1][2] += a.y * bb.z; acc[1][3] += a.y * bb.w;
        acc[2][0] += a.z * bb.x; acc[2][1] += a.z * bb.y; acc[2][2] += a.z * bb.z; acc[2][3] += a.z * bb.w;
        acc[3][0] += a.w * bb.x; acc[3][1] += a.w * bb.y; acc[3][2] += a.w * bb.z; acc[3][3] += a.w * bb.w;
        nrm[0] += a.x * ko; nrm[1] += a.y * ko; nrm[2] += a.z * ko; nrm[3] += a.w * ko;
    }

    float* ob = out + ((size_t)bh * SDIM + s_base) * DDIM;
    #pragma unroll
    for (int i = 0; i < 4; ++i) {
        const float inv = 1.0f / (nrm[i] + 1e-8f);
        float4 o;
        o.x = acc[i][0] * inv;
        o.y = acc[i][1] * inv;
        o.z = acc[i][2] * inv;
        o.w = acc[i][3] * inv;
        *(float4*)(ob + (size_t)(r0 + i) * DDIM + e0) = o;
    }
}

extern "C" void kernel_launch(void* const* d_in, const int* in_sizes, int n_in,
                              void* d_out, int out_size, void* d_ws, size_t ws_size,
                              hipStream_t stream) {
    const float* Q = (const float*)d_in[0];
    const float* K = (const float*)d_in[1];
    const float* V = (const float*)d_in[2];
    const float* M = (const float*)d_in[3];
    float* out  = (float*)d_out;
    float* kv   = (float*)d_ws;                                  // NBH*64*64 floats
    float* kone = kv + (size_t)NBH * DDIM * DDIM;                // NBH*64 floats

    const size_t zero_bytes =
        ((size_t)NBH * DDIM * DDIM + (size_t)NBH * DDIM) * sizeof(float);
    hipMemsetAsync(d_ws, 0, zero_bytes, stream);

    dim3 g1(P1_NCHUNK, NBH);
    la_phase1<<<g1, dim3(256), 0, stream>>>(K, V, M, kv, kone);

    dim3 g2(SDIM / P2_MT, NBH);
    la_phase2<<<g2, dim3(256), 0, stream>>>(Q, M, kv, kone, out);
}

// Round 2
// 247.974 us; speedup vs baseline: 1.1230x; 1.1230x over previous
//
#include <hip/hip_runtime.h>

#define BDIM 4
#define HDIM 16
#define SDIM 4096
#define DDIM 64
#define NBH (BDIM * HDIM)

#define P1_TS 16
#define BH_STRIDE (DDIM * DDIM + DDIM)      // 4160 floats: [kv 64x64][kone 64]
#define CHUNK_FLOATS (NBH * BH_STRIDE)      // 266240 floats = 1,064,960 B
#define P2_MT 128                           // q rows per phase2 block

__device__ __forceinline__ float phi_f(float x) {
    // elu(x)+1 = x+1 (x>0) else exp(x)
    return x > 0.0f ? x + 1.0f : __expf(x);
}

// -------- Phase 1: partial kv[d][e] = sum_s phiK[s][d]*V[s][e]; kone[d] = sum_s phiK[s][d]
// ATOMIC=false: store partial into outp[(chunk*NBH + bh)*BH_STRIDE]
// ATOMIC=true : atomicAdd into outp[bh*BH_STRIDE] (requires pre-zeroed buffer)
template<bool ATOMIC>
__global__ __launch_bounds__(256) void la_phase1(
    const float* __restrict__ K, const float* __restrict__ V,
    const float* __restrict__ mask, float* __restrict__ outp, int chunk_rows)
{
    __shared__ float kT[2][P1_TS][DDIM];    // double-buffered: 2 x 4 KB
    __shared__ float vT[2][P1_TS][DDIM];    // 2 x 4 KB

    const int bh  = blockIdx.y;
    const int b   = bh / HDIM;
    const int t   = threadIdx.x;
    const int row = t >> 4;                 // 0..15 (tile row this thread loads)
    const int c4  = (t & 15) << 2;          // 0..60 (col group this thread loads)
    const int d0  = row << 2;               // acc tile d rows
    const int e0  = c4;                     // acc tile e cols
    const int s_base = blockIdx.x * chunk_rows;

    const float* Kb = K + (size_t)bh * SDIM * DDIM;
    const float* Vb = V + (size_t)bh * SDIM * DDIM;
    const float* mb = mask + (size_t)b * SDIM;

    const float scale = 0.35355339059327373f;   // 64^-0.25

    float acc[4][4] = {};
    float k1[4] = {0.f, 0.f, 0.f, 0.f};

    // prefetch tile 0
    int s0 = s_base + row;
    float4 kf = *(const float4*)(Kb + (size_t)s0 * DDIM + c4);
    float4 vf = *(const float4*)(Vb + (size_t)s0 * DDIM + c4);
    float  m  = mb[s0];

    const int ntiles = chunk_rows >> 4;
    int p = 0;
    for (int tt = 0; tt < ntiles; ++tt) {
        const float p0 = phi_f(kf.x * scale) * m;
        const float p1 = phi_f(kf.y * scale) * m;
        const float p2 = phi_f(kf.z * scale) * m;
        const float p3 = phi_f(kf.w * scale) * m;
        kT[p][row][c4 + 0] = p0;
        kT[p][row][c4 + 1] = p1;
        kT[p][row][c4 + 2] = p2;
        kT[p][row][c4 + 3] = p3;
        *(float4*)&vT[p][row][c4] = vf;
        k1[0] += p0; k1[1] += p1; k1[2] += p2; k1[3] += p3;
        __syncthreads();        // single barrier per tile (double-buffer correctness)

        // prefetch next tile; vmcnt wait lands at next iteration's phi, after the FMA block
        if (tt + 1 < ntiles) {
            const int sn = s_base + ((tt + 1) << 4) + row;
            kf = *(const float4*)(Kb + (size_t)sn * DDIM + c4);
            vf = *(const float4*)(Vb + (size_t)sn * DDIM + c4);
            m  = mb[sn];
        }

        #pragma unroll
        for (int ss = 0; ss < P1_TS; ++ss) {
            const float4 a  = *(const float4*)&kT[p][ss][d0];  // 4-addr broadcast (free)
            const float4 v4 = *(const float4*)&vT[p][ss][e0];  // 2-way alias (free)
            acc[0][0] += a.x * v4.x; acc[0][1] += a.x * v4.y; acc[0][2] += a.x * v4.z; acc[0][3] += a.x * v4.w;
            acc[1][0] += a.y * v4.x; acc[1][1] += a.y * v4.y; acc[1][2] += a.y * v4.z; acc[1][3] += a.y * v4.w;
            acc[2][0] += a.z * v4.x; acc[2][1] += a.z * v4.y; acc[2][2] += a.z * v4.z; acc[2][3] += a.z * v4.w;
            acc[3][0] += a.w * v4.x; acc[3][1] += a.w * v4.y; acc[3][2] += a.w * v4.z; acc[3][3] += a.w * v4.w;
        }
        p ^= 1;
    }

    float* base = ATOMIC ? (outp + (size_t)bh * BH_STRIDE)
                         : (outp + ((size_t)blockIdx.x * NBH + bh) * BH_STRIDE);
    if (ATOMIC) {
        #pragma unroll
        for (int i = 0; i < 4; ++i)
            #pragma unroll
            for (int j = 0; j < 4; ++j)
                atomicAdd(&base[(d0 + i) * DDIM + e0 + j], acc[i][j]);
    } else {
        #pragma unroll
        for (int i = 0; i < 4; ++i)
            *(float4*)&base[(d0 + i) * DDIM + e0] =
                make_float4(acc[i][0], acc[i][1], acc[i][2], acc[i][3]);
    }

    // reduce k1 over the 16 row-groups sharing each column
    __syncthreads();
    kT[0][row][c4 + 0] = k1[0];
    kT[0][row][c4 + 1] = k1[1];
    kT[0][row][c4 + 2] = k1[2];
    kT[0][row][c4 + 3] = k1[3];
    __syncthreads();
    if (t < DDIM) {
        float s1 = 0.f;
        #pragma unroll
        for (int r = 0; r < P1_TS; ++r) s1 += kT[0][r][t];
        if (ATOMIC) atomicAdd(&base[DDIM * DDIM + t], s1);
        else        base[DDIM * DDIM + t] = s1;
    }
}

// -------- Reduce: fin[i] = sum_c part[c][i], i over NBH*BH_STRIDE, float4-ized
__global__ __launch_bounds__(256) void la_reduce(
    const float* __restrict__ part, float* __restrict__ fin, int nc)
{
    const int g = blockIdx.x * 256 + threadIdx.x;     // float4 index, 66560 total
    const float4* p4 = (const float4*)part;
    float4 s = p4[g];
    for (int c = 1; c < nc; ++c) {
        const float4 v = p4[(size_t)c * (CHUNK_FLOATS / 4) + g];
        s.x += v.x; s.y += v.y; s.z += v.z; s.w += v.w;
    }
    ((float4*)fin)[g] = s;
}

// -------- Phase 2: out[s][e] = (sum_d phiQ[s][d]*kv[d][e]) / (sum_d phiQ[s][d]*kone[d] + 1e-8)
__global__ __launch_bounds__(512) void la_phase2(
    const float* __restrict__ Q, const float* __restrict__ mask,
    const float* __restrict__ fin_all, float* __restrict__ out)
{
    __shared__ float kvL[DDIM][DDIM];           // 16 KB
    __shared__ float pqT[DDIM][P2_MT + 4];      // 33 KB, stride 132: 2-way writes (free)
    __shared__ float koL[DDIM];

    const int bh = blockIdx.y;
    const int b  = bh / HDIM;
    const int t  = threadIdx.x;
    const int s_base = blockIdx.x * P2_MT;

    const float scale = 0.35355339059327373f;
    const float* fin = fin_all + (size_t)bh * BH_STRIDE;

    // load kv (1024 float4) + kone into LDS
    {
        const float4* src = (const float4*)fin;
        float4* dst = (float4*)&kvL[0][0];
        dst[t] = src[t];
        dst[t + 512] = src[t + 512];
        if (t < DDIM) koL[t] = fin[DDIM * DDIM + t];
    }
    // load q tile (coalesced 64B/row-quarter), apply phi+mask, store transposed
    {
        const float* Qb = Q + (size_t)bh * SDIM * DDIM;
        const float* mb = mask + (size_t)b * SDIM;
        const int lr   = t & 15;                // row within 16-row group
        const int c4   = ((t >> 4) & 15) << 2;  // col group 0..60
        const int half = t >> 8;                // 0/1: row groups 0-3 / 4-7
        #pragma unroll
        for (int k = 0; k < 4; ++k) {
            const int r = lr + 16 * (half * 4 + k);   // 0..127
            const int s = s_base + r;
            const float4 qf = *(const float4*)(Qb + (size_t)s * DDIM + c4);
            const float mm = mb[s];
            pqT[c4 + 0][r] = phi_f(qf.x * scale) * mm;
            pqT[c4 + 1][r] = phi_f(qf.y * scale) * mm;
            pqT[c4 + 2][r] = phi_f(qf.z * scale) * mm;
            pqT[c4 + 3][r] = phi_f(qf.w * scale) * mm;
        }
    }
    __syncthreads();

    const int r0 = (t >> 4) << 2;   // 0..124
    const int e0 = (t & 15) << 2;   // 0..60
    float acc[4][4] = {};
    float nrm[4] = {0.f, 0.f, 0.f, 0.f};

    #pragma unroll 16
    for (int d = 0; d < DDIM; ++d) {
        const float4 a  = *(const float4*)&pqT[d][r0];   // broadcast within wave
        const float4 bb = *(const float4*)&kvL[d][e0];   // 2-way alias (free)
        const float ko = koL[d];                          // same-addr broadcast
        acc[0][0] += a.x * bb.x; acc[0][1] += a.x * bb.y; acc[0][2] += a.x * bb.z; acc[0][3] += a.x * bb.w;
        acc[1][0] += a.y * bb.x; acc[1][1] += a.y * bb.y; acc[1][2] += a.y * bb.z; acc[1][3] += a.y * bb.w;
        acc[2][0] += a.z * bb.x; acc[2][1] += a.z * bb.y; acc[2][2] += a.z * bb.z; acc[2][3] += a.z * bb.w;
        acc[3][0] += a.w * bb.x; acc[3][1] += a.w * bb.y; acc[3][2] += a.w * bb.z; acc[3][3] += a.w * bb.w;
        nrm[0] += a.x * ko; nrm[1] += a.y * ko; nrm[2] += a.z * ko; nrm[3] += a.w * ko;
    }

    float* ob = out + ((size_t)bh * SDIM + s_base) * DDIM;
    #pragma unroll
    for (int i = 0; i < 4; ++i) {
        const float inv = 1.0f / (nrm[i] + 1e-8f);
        float4 o;
        o.x = acc[i][0] * inv;
        o.y = acc[i][1] * inv;
        o.z = acc[i][2] * inv;
        o.w = acc[i][3] * inv;
        *(float4*)(ob + (size_t)(r0 + i) * DDIM + e0) = o;
    }
}

extern "C" void kernel_launch(void* const* d_in, const int* in_sizes, int n_in,
                              void* d_out, int out_size, void* d_ws, size_t ws_size,
                              hipStream_t stream) {
    const float* Q = (const float*)d_in[0];
    const float* K = (const float*)d_in[1];
    const float* V = (const float*)d_in[2];
    const float* M = (const float*)d_in[3];
    float* out = (float*)d_out;

    const size_t chunk_bytes = (size_t)CHUNK_FLOATS * sizeof(float);  // 1,064,960 B

    // ws_size is constant across calls -> same path every call (graph-safe)
    int nc = 0;
    if      (ws_size >= 33 * chunk_bytes) nc = 32;   // 35.1 MB: partials + final
    else if (ws_size >= 17 * chunk_bytes) nc = 16;   // 18.1 MB

    if (nc > 0) {
        float* part = (float*)d_ws;
        float* fin  = part + (size_t)nc * CHUNK_FLOATS;
        la_phase1<false><<<dim3(nc, NBH), dim3(256), 0, stream>>>(K, V, M, part, SDIM / nc);
        la_reduce<<<dim3(CHUNK_FLOATS / 4 / 256), dim3(256), 0, stream>>>(part, fin, nc);
        la_phase2<<<dim3(SDIM / P2_MT, NBH), dim3(512), 0, stream>>>(Q, M, fin, out);
    } else {
        // fallback: atomic accumulation directly into final buffer (1.06 MB)
        float* fin = (float*)d_ws;
        hipMemsetAsync(d_ws, 0, chunk_bytes, stream);
        la_phase1<true><<<dim3(16, NBH), dim3(256), 0, stream>>>(K, V, M, fin, SDIM / 16);
        la_phase2<<<dim3(SDIM / P2_MT, NBH), dim3(512), 0, stream>>>(Q, M, fin, out);
    }
}